// Round 2
// baseline (59.193 us; speedup 1.0000x reference)
//
#include <hip/hip_runtime.h>

#define C_S 384
#define C_H 128
#define NROWS 512

typedef float f4 __attribute__((ext_vector_type(4)));

// Kernel A: per-row  y = W·s + b  -> LayerNorm -> z = (Wout_half · ln)/D (+bout)
// bid < 512:  row of s1 with W1/b1, Wout[:, :128], add bout  -> u'
// bid >= 512: row of s2 with W2/b2, Wout[:, 128:], no bout   -> v
__global__ __launch_bounds__(128) void proj_ln_out(
    const float* __restrict__ s1, const float* __restrict__ s2,
    const float* __restrict__ W1, const float* __restrict__ b1,
    const float* __restrict__ W2, const float* __restrict__ b2,
    const float* __restrict__ gamma, const float* __restrict__ beta,
    const float* __restrict__ Wout, const float* __restrict__ bout,
    float* __restrict__ u, float* __restrict__ v)
{
    const int bid = blockIdx.x;
    const int t   = threadIdx.x;
    const bool isA = (bid < NROWS);
    const int r = isA ? bid : (bid - NROWS);
    const float* __restrict__ src  = isA ? s1 : s2;
    const float* __restrict__ W    = isA ? W1 : W2;
    const float* __restrict__ bias = isA ? b1 : b2;
    float* __restrict__ dst = isA ? u : v;
    const int wout_off = isA ? 0 : C_H;

    __shared__ float srow[C_S];
    __shared__ float lnv[C_H];
    __shared__ float part[4];   // {sum, sumsq} x 2 waves

    // stage the 384-float input row (coalesced)
    srow[t]       = src[r * C_S + t];
    srow[t + 128] = src[r * C_S + t + 128];
    srow[t + 256] = src[r * C_S + t + 256];
    __syncthreads();

    // projection: thread t computes output channel t (K = 384)
    float y = bias[t];
    const float* wrow = W + t * C_S;
    #pragma unroll 8
    for (int k = 0; k < C_S; k += 4) {
        f4 w = *reinterpret_cast<const f4*>(wrow + k);
        y += w.x * srow[k] + w.y * srow[k + 1] + w.z * srow[k + 2] + w.w * srow[k + 3];
    }

    // single-pass LayerNorm stats: sum & sumsq, wave shfl reduce + LDS combine
    float sv = y, qv = y * y;
    #pragma unroll
    for (int off = 32; off > 0; off >>= 1) {
        sv += __shfl_down(sv, off);
        qv += __shfl_down(qv, off);
    }
    if ((t & 63) == 0) {
        part[(t >> 6) * 2]     = sv;
        part[(t >> 6) * 2 + 1] = qv;
    }
    __syncthreads();
    const float mu  = (part[0] + part[2]) * (1.0f / C_H);
    const float ms  = (part[1] + part[3]) * (1.0f / C_H);
    const float var = ms - mu * mu;
    lnv[t] = (y - mu) * rsqrtf(var + 1e-5f) * gamma[t] + beta[t];
    __syncthreads();

    // output projection: thread t computes out-channel t over the 128 LN'd values
    const float invD = (float)(1.0 / (0.001 + 262144.0));
    float acc = 0.f;
    const float* wo = Wout + t * (2 * C_H) + wout_off;
    #pragma unroll 8
    for (int h = 0; h < C_H; h += 4) {
        f4 w = *reinterpret_cast<const f4*>(wo + h);
        acc += w.x * lnv[h] + w.y * lnv[h + 1] + w.z * lnv[h + 2] + w.w * lnv[h + 3];
    }
    dst[r * C_H + t] = acc * invD + (isA ? bout[t] : 0.f);
}

// Kernel B: out[n,m,z] = u'[n,z] + v[m,z]   (134 MB streaming write)
// Tile: NT=8 n-rows x MT=32 m-rows per block. v tile held in registers
// (4 x float4/thread) and reused across all 8 n-rows -> v read traffic /8.
#define NT 8
#define MT 32
__global__ __launch_bounds__(256) void bcast_add(
    const float* __restrict__ u, const float* __restrict__ v,
    float* __restrict__ out)
{
    const int n0 = (blockIdx.x >> 4) * NT;   // 64 n-tiles
    const int m0 = (blockIdx.x & 15) * MT;   // 16 m-tiles
    const int zq = threadIdx.x & 31;         // z/4
    const int ml = threadIdx.x >> 5;         // 0..7

    const f4* __restrict__ vq = reinterpret_cast<const f4*>(v);
    const f4* __restrict__ uq = reinterpret_cast<const f4*>(u);

    // preload v tile: m = m0 + ml + 8k, k = 0..3
    f4 v4[4];
    #pragma unroll
    for (int k = 0; k < 4; ++k)
        v4[k] = vq[(size_t)(m0 + ml + 8 * k) * 32 + zq];

    #pragma unroll
    for (int n = n0; n < n0 + NT; ++n) {
        const f4 u4 = uq[(size_t)n * 32 + zq];
        f4* __restrict__ oq = reinterpret_cast<f4*>(out)
                              + (size_t)n * 512 * 32 + (size_t)m0 * 32;
        #pragma unroll
        for (int k = 0; k < 4; ++k) {
            f4 o = u4 + v4[k];
            __builtin_nontemporal_store(o, &oq[(size_t)(ml + 8 * k) * 32 + zq]);
        }
    }
}

extern "C" void kernel_launch(void* const* d_in, const int* in_sizes, int n_in,
                              void* d_out, int out_size, void* d_ws, size_t ws_size,
                              hipStream_t stream) {
    const float* s1    = (const float*)d_in[0];
    const float* s2    = (const float*)d_in[1];
    const float* W1    = (const float*)d_in[2];
    const float* b1    = (const float*)d_in[3];
    const float* W2    = (const float*)d_in[4];
    const float* b2    = (const float*)d_in[5];
    const float* gamma = (const float*)d_in[6];
    const float* beta  = (const float*)d_in[7];
    const float* Wout  = (const float*)d_in[8];
    const float* bout  = (const float*)d_in[9];

    float* u = (float*)d_ws;                 // 512*128 fp32
    float* v = u + NROWS * C_H;              // 512*128 fp32

    proj_ln_out<<<2 * NROWS, 128, 0, stream>>>(s1, s2, W1, b1, W2, b2,
                                               gamma, beta, Wout, bout, u, v);
    bcast_add<<<(NROWS / NT) * (NROWS / MT), 256, 0, stream>>>(u, v, (float*)d_out);
}

// Round 3
// 42.636 us; speedup vs baseline: 1.3883x; 1.3883x over previous
//
#include <hip/hip_runtime.h>

#define C_S 384
#define C_H 128
#define NROWS 512
#define R 4            // rows per block in kernel A (== wave count)

typedef float f4 __attribute__((ext_vector_type(4)));

// Kernel A: per-row  y = W·s + b -> LayerNorm -> z = (Wout_half · ln)/D (+bout)
// 256 blocks: bid<128 -> 4 rows of s1 (u-side), else 4 rows of s2 (v-side).
// Layout: 4 waves x 4 lane-groups(16) ; group owns one channel per iter,
// lane j owns k-slice [24j, 24j+24). All global W reads coalesced.
__global__ __launch_bounds__(256) void proj_ln_out(
    const float* __restrict__ s1, const float* __restrict__ s2,
    const float* __restrict__ W1, const float* __restrict__ b1,
    const float* __restrict__ W2, const float* __restrict__ b2,
    const float* __restrict__ gamma, const float* __restrict__ beta,
    const float* __restrict__ Wout, const float* __restrict__ bout,
    float* __restrict__ u, float* __restrict__ v)
{
    const int bid = blockIdx.x;
    const int nb_side = NROWS / R;              // 128
    const bool isA = bid < nb_side;
    const int r0 = (isA ? bid : bid - nb_side) * R;
    const float* __restrict__ src  = isA ? s1 : s2;
    const float* __restrict__ W    = isA ? W1 : W2;
    const float* __restrict__ bias = isA ? b1 : b2;
    float* __restrict__ dst = isA ? u : v;
    const int wout_off = isA ? 0 : C_H;

    const int tid  = threadIdx.x;
    const int wv   = tid >> 6;    // wave 0..3
    const int lane = tid & 63;
    const int g    = lane >> 4;   // lane-group 0..3
    const int j    = lane & 15;   // lane-in-group

    __shared__ __align__(16) float ylds[R][C_H];
    __shared__ __align__(16) float lnv[R][C_H];

    // s k-slices in registers: rows r0..r0+3, k = 24j..24j+23 (6 x float4)
    f4 sreg[R][6];
    #pragma unroll
    for (int r = 0; r < R; ++r) {
        const float* p = src + (r0 + r) * C_S + j * 24;
        #pragma unroll
        for (int q = 0; q < 6; ++q)
            sreg[r][q] = *reinterpret_cast<const f4*>(p + 4 * q);
    }

    // ---- GEMM 1: y[r][h] = W[h] . s[r]  (K = 384) ----
    #pragma unroll 2
    for (int i = 0; i < 8; ++i) {
        const int h = wv * 32 + i * 4 + g;
        const float* wp = W + h * C_S + j * 24;
        f4 wr[6];
        #pragma unroll
        for (int q = 0; q < 6; ++q)
            wr[q] = *reinterpret_cast<const f4*>(wp + 4 * q);
        float acc[R];
        #pragma unroll
        for (int r = 0; r < R; ++r) {
            f4 a = wr[0] * sreg[r][0];
            #pragma unroll
            for (int q = 1; q < 6; ++q) a += wr[q] * sreg[r][q];
            acc[r] = (a.x + a.y) + (a.z + a.w);
        }
        #pragma unroll
        for (int off = 1; off < 16; off <<= 1)
            #pragma unroll
            for (int r = 0; r < R; ++r)
                acc[r] += __shfl_xor(acc[r], off);
        if (j == 0) {
            #pragma unroll
            for (int r = 0; r < R; ++r) ylds[r][h] = acc[r];
        }
    }
    __syncthreads();

    // ---- LayerNorm: wave wv handles row wv (R == 4 waves) ----
    {
        const int r = wv;
        const float y0 = ylds[r][lane]      + bias[lane];
        const float y1 = ylds[r][lane + 64] + bias[lane + 64];
        float s = y0 + y1, q = y0 * y0 + y1 * y1;
        #pragma unroll
        for (int off = 1; off < 64; off <<= 1) {
            s += __shfl_xor(s, off);
            q += __shfl_xor(q, off);
        }
        const float mu  = s * (1.0f / C_H);
        const float var = q * (1.0f / C_H) - mu * mu;
        const float rs  = rsqrtf(var + 1e-5f);
        lnv[r][lane]      = (y0 - mu) * rs * gamma[lane]      + beta[lane];
        lnv[r][lane + 64] = (y1 - mu) * rs * gamma[lane + 64] + beta[lane + 64];
    }
    __syncthreads();

    // ---- GEMM 2: z[r][zc] = Wout[zc, off:off+128] . lnv[r]  (K = 128) ----
    // lane j owns k-slice [8j, 8j+8) (2 x float4)
    f4 lreg[R][2];
    #pragma unroll
    for (int r = 0; r < R; ++r) {
        lreg[r][0] = *reinterpret_cast<const f4*>(&lnv[r][j * 8]);
        lreg[r][1] = *reinterpret_cast<const f4*>(&lnv[r][j * 8 + 4]);
    }
    const float invD = (float)(1.0 / (0.001 + 262144.0));
    #pragma unroll 2
    for (int i = 0; i < 8; ++i) {
        const int zc = wv * 32 + i * 4 + g;
        const float* wp = Wout + zc * (2 * C_H) + wout_off + j * 8;
        const f4 w0 = *reinterpret_cast<const f4*>(wp);
        const f4 w1 = *reinterpret_cast<const f4*>(wp + 4);
        float acc[R];
        #pragma unroll
        for (int r = 0; r < R; ++r) {
            f4 a = w0 * lreg[r][0] + w1 * lreg[r][1];
            acc[r] = (a.x + a.y) + (a.z + a.w);
        }
        #pragma unroll
        for (int off = 1; off < 16; off <<= 1)
            #pragma unroll
            for (int r = 0; r < R; ++r)
                acc[r] += __shfl_xor(acc[r], off);
        if (j == 0) {
            #pragma unroll
            for (int r = 0; r < R; ++r)
                dst[(r0 + r) * C_H + zc] = acc[r] * invD + (isA ? bout[zc] : 0.f);
        }
    }
}

// Kernel B: out[n,m,z] = u'[n,z] + v[m,z]   (134 MB streaming write)
// BN=4 n-rows x BM=32 m-rows per block; v tile in registers reused over n.
#define BN 4
#define BM 32
__global__ __launch_bounds__(256) void bcast_add(
    const float* __restrict__ u, const float* __restrict__ v,
    float* __restrict__ out)
{
    const int n0 = (blockIdx.x >> 4) * BN;   // 128 n-tiles
    const int m0 = (blockIdx.x & 15) * BM;   // 16 m-tiles
    const int zq = threadIdx.x & 31;         // z/4
    const int ml = threadIdx.x >> 5;         // 0..7

    const f4* __restrict__ vq = reinterpret_cast<const f4*>(v);
    const f4* __restrict__ uq = reinterpret_cast<const f4*>(u);

    f4 v4[4];
    #pragma unroll
    for (int k = 0; k < 4; ++k)
        v4[k] = vq[(size_t)(m0 + ml + 8 * k) * 32 + zq];

    #pragma unroll
    for (int n = n0; n < n0 + BN; ++n) {
        const f4 u4 = uq[(size_t)n * 32 + zq];
        f4* __restrict__ oq = reinterpret_cast<f4*>(out)
                              + (size_t)n * (NROWS * 32) + (size_t)m0 * 32;
        #pragma unroll
        for (int k = 0; k < 4; ++k)
            oq[(size_t)(ml + 8 * k) * 32 + zq] = u4 + v4[k];
    }
}

extern "C" void kernel_launch(void* const* d_in, const int* in_sizes, int n_in,
                              void* d_out, int out_size, void* d_ws, size_t ws_size,
                              hipStream_t stream) {
    const float* s1    = (const float*)d_in[0];
    const float* s2    = (const float*)d_in[1];
    const float* W1    = (const float*)d_in[2];
    const float* b1    = (const float*)d_in[3];
    const float* W2    = (const float*)d_in[4];
    const float* b2    = (const float*)d_in[5];
    const float* gamma = (const float*)d_in[6];
    const float* beta  = (const float*)d_in[7];
    const float* Wout  = (const float*)d_in[8];
    const float* bout  = (const float*)d_in[9];

    float* u = (float*)d_ws;                 // 512*128 fp32
    float* v = u + NROWS * C_H;              // 512*128 fp32

    proj_ln_out<<<2 * (NROWS / R), 256, 0, stream>>>(s1, s2, W1, b1, W2, b2,
                                                     gamma, beta, Wout, bout, u, v);
    bcast_add<<<(NROWS / BN) * (NROWS / BM), 256, 0, stream>>>(u, v, (float*)d_out);
}